// Round 12
// baseline (591.716 us; speedup 1.0000x reference)
//
#include <hip/hip_runtime.h>
#include <hip/hip_bf16.h>
#include <stdint.h>

typedef __attribute__((ext_vector_type(8))) short short8;
typedef __attribute__((ext_vector_type(4))) short short4v;
typedef __attribute__((ext_vector_type(4))) float floatx4;

#define GLOAD_LDS16(gptr, lptr)                                                     \
  __builtin_amdgcn_global_load_lds(                                                 \
      (const __attribute__((address_space(1))) void*)(gptr),                        \
      (__attribute__((address_space(3))) void*)(lptr), 16, 0, 0)

#define FENCE() asm volatile("" ::: "memory")
#define BARRIER() do { FENCE(); __builtin_amdgcn_s_barrier(); FENCE(); } while (0)
#define PHASE_END() do { __builtin_amdgcn_sched_barrier(0);                        \
                         asm volatile("s_waitcnt lgkmcnt(0)" ::: "memory");        \
                         __builtin_amdgcn_s_barrier();                             \
                         __builtin_amdgcn_sched_barrier(0); } while (0)

__device__ inline void fwht16(float v[16]) {
#pragma unroll
    for (int s = 0; s < 4; ++s) {
        const int h = 1 << s;
#pragma unroll
        for (int k = 0; k < 16; k += 2 * h)
#pragma unroll
            for (int j = 0; j < h; ++j) {
                float a = v[k + j], b = v[k + j + h];
                v[k + j] = a + b;
                v[k + j + h] = a - b;
            }
    }
}

__device__ inline void fwht16v(floatx4 v[16]) {
#pragma unroll
    for (int s = 0; s < 4; ++s) {
        const int h = 1 << s;
#pragma unroll
        for (int k = 0; k < 16; k += 2 * h)
#pragma unroll
            for (int j = 0; j < h; ++j) {
                floatx4 a = v[k + j], b = v[k + j + h];
                v[k + j] = a + b;
                v[k + j + h] = a - b;
            }
    }
}

// ---------------------------------------------------------------------------
// Kernel 1: W_tmp(fp32) = Wscale*CB[Qidxs] + (A@B) via bf16 MFMA.
// Same as measured R11 decode_mfma, except the store is fp32 into W_tmp
// (the column-FWHT passes need fp32 so W only gets ONE bf16 rounding at
// the very end, after H-mixing).
// ---------------------------------------------------------------------------
__global__ __launch_bounds__(512) void decode_mfma(
    const int* __restrict__ Qidxs, const float* __restrict__ D4_CB,
    const float* __restrict__ Wscale_p, const float* __restrict__ A,
    const float* __restrict__ B, float* __restrict__ W_tmp)
{
    __shared__ __align__(16) __hip_bfloat16 la[256 * 72];
    __shared__ __align__(16) __hip_bfloat16 lbt[256 * 72];
    __shared__ __align__(16) float CBs[1024];

    const int t = threadIdx.x;
    const int lane = t & 63;
    const int wv = t >> 6;
    const int wm = wv >> 2;           // 0..1  (o-half)
    const int wn = wv & 3;            // 0..3  (i-quarter)
    const long oBase = (long)blockIdx.y * 256;
    const long iBase = (long)blockIdx.x * 256;

#pragma unroll
    for (int u = 0; u < 8; ++u) {
        int el4 = u * 512 + t;          // float4 index, 4096 total
        int row = el4 >> 4;
        int r   = (el4 & 15) * 4;
        float4 v = *(const float4*)(A + (oBase + row) * 64 + r);
        __hip_bfloat16* d = &la[row * 72 + r];
        d[0] = __float2bfloat16(v.x); d[1] = __float2bfloat16(v.y);
        d[2] = __float2bfloat16(v.z); d[3] = __float2bfloat16(v.w);
    }
#pragma unroll
    for (int u = 0; u < 32; ++u) {
        int el = u * 512 + t;           // 0..16383
        int r = el >> 8;
        int j = el & 255;
        lbt[j * 72 + r] = __float2bfloat16(B[(long)r * 4096 + iBase + j]);
    }
    if (t < 256) ((float4*)CBs)[t] = ((const float4*)D4_CB)[t];
    __syncthreads();

    const float wscale = Wscale_p[0];
    const int fr = lane & 15;
    const int c2 = lane >> 4;
    floatx4 acc[8][4] = {};
    short8 af[4][2], bfx[4][2];

#pragma unroll
    for (int n = 0; n < 4; ++n)
#pragma unroll
        for (int kh = 0; kh < 2; ++kh)
            bfx[n][kh] = *(const short8*)&lbt[(wn * 64 + n * 16 + fr) * 72 + kh * 32 + c2 * 8];

#pragma unroll
    for (int mh = 0; mh < 2; ++mh) {
#pragma unroll
        for (int m = 0; m < 4; ++m)
#pragma unroll
            for (int kh = 0; kh < 2; ++kh)
                af[m][kh] = *(const short8*)&la[(wm * 128 + mh * 64 + m * 16 + fr) * 72 + kh * 32 + c2 * 8];
#pragma unroll
        for (int m = 0; m < 4; ++m)
#pragma unroll
            for (int n = 0; n < 4; ++n)
#pragma unroll
                for (int kh = 0; kh < 2; ++kh)
                    acc[mh * 4 + m][n] = __builtin_amdgcn_mfma_f32_16x16x32_bf16(
                        af[m][kh], bfx[n][kh], acc[mh * 4 + m][n], 0, 0, 0);
    }

    const int q4 = c2 * 4;
#pragma unroll
    for (int m = 0; m < 8; ++m)
#pragma unroll
        for (int n = 0; n < 4; ++n)
#pragma unroll
            for (int rr = 0; rr < 4; ++rr) {
                const long o = oBase + wm * 128 + m * 16 + q4 + rr;
                const long i = iBase + wn * 64 + n * 16 + fr;
                const int q = Qidxs[o * 1024 + (i >> 2)];
                W_tmp[o * 4096 + i] = wscale * CBs[q * 4 + (i & 3)] + acc[m][n][rr];
            }
}

// ---------------------------------------------------------------------------
// Kernel 1b (NEW): column-FWHT pass over the o-index of W_tmp [4096][4096].
// out = fwht(z)*SV folds into W: W4 = diag(SV) . (H W_eff) / 64.
// Radix-16, 3 passes (s4 = 0, 4, 8 -> stride 1, 16, 256 over o).
// Block = (group g of 16 o-rows, column chunk of 1024); thread = 4 fp32 cols.
// Rows contiguous -> all loads/stores coalesced float4. Passes 1-2 fp32
// in-place (disjoint element sets per block -> safe); pass 3 scales by
// SV[o]/64 and emits bf16 W4 (the single bf16 rounding on the W path).
// ---------------------------------------------------------------------------
__global__ __launch_bounds__(256) void wfwht_col_pass(
    const float* __restrict__ Win, float* __restrict__ Wf,
    __hip_bfloat16* __restrict__ Wb, const float* __restrict__ SV,
    int s4, int last)
{
    const int g = blockIdx.x;                    // 0..255
    const int col = blockIdx.y * 1024 + threadIdx.x * 4;
    const int st = 1 << s4;
    const int base_o = ((g >> s4) << (s4 + 4)) | (g & (st - 1));

    floatx4 v[16];
#pragma unroll
    for (int j = 0; j < 16; ++j)
        v[j] = *(const floatx4*)(Win + (long)(base_o + j * st) * 4096 + col);
    fwht16v(v);

    if (!last) {
#pragma unroll
        for (int j = 0; j < 16; ++j)
            *(floatx4*)(Wf + (long)(base_o + j * st) * 4096 + col) = v[j];
    } else {
#pragma unroll
        for (int j = 0; j < 16; ++j) {
            const long o = base_o + (long)j * st;
            const float sc = SV[o] * 0.015625f;   // SV[o] / 64
            short4v p;
#pragma unroll
            for (int c = 0; c < 4; ++c) {
                __hip_bfloat16 b = __float2bfloat16(v[j][c] * sc);
                p[c] = *(short*)&b;
            }
            *(short4v*)(Wb + o * 4096 + col) = p;
        }
    }
}

// ---------------------------------------------------------------------------
// Kernel 2: per row: x*(SU/scaleWH) -> FWHT(4096) -> *1/64 -> bf16.
// R11 change: fp32 division replaced by v_rcp (sWH in [0.5,1.5], rel err
// ~1e-7 — removes ~16 full div sequences/thread of VALU work).
// ---------------------------------------------------------------------------
__global__ __launch_bounds__(256) void fwht_in_kernel(
    const float* __restrict__ x, const float* __restrict__ SU,
    const float* __restrict__ sWH, __hip_bfloat16* __restrict__ xh)
{
    __shared__ float row[4096 + 256];
    const int t = threadIdx.x;
    const long base = (long)blockIdx.x * 4096;
    float v[16];

#pragma unroll
    for (int u = 0; u < 16; ++u) {
        int e = u * 256 + t;
        v[u] = x[base + e] * (SU[e] * __builtin_amdgcn_rcpf(sWH[e]));
    }
    fwht16(v);
#pragma unroll
    for (int u = 0; u < 16; ++u) {
        int e = u * 256 + t;
        row[e + (e >> 4)] = v[u];
    }
    __syncthreads();

    const int lo = t & 15, hi = t >> 4;
#pragma unroll
    for (int u = 0; u < 16; ++u) v[u] = row[hi * 272 + u * 17 + lo];
    fwht16(v);
#pragma unroll
    for (int u = 0; u < 16; ++u) row[hi * 272 + u * 17 + lo] = v[u];
    __syncthreads();

#pragma unroll
    for (int u = 0; u < 16; ++u) v[u] = row[t * 17 + u];
    fwht16(v);

    short8 o0, o1;
#pragma unroll
    for (int u = 0; u < 8; ++u) {
        __hip_bfloat16 b = __float2bfloat16(v[u] * 0.015625f);
        o0[u] = *(short*)&b;
    }
#pragma unroll
    for (int u = 0; u < 8; ++u) {
        __hip_bfloat16 b = __float2bfloat16(v[8 + u] * 0.015625f);
        o1[u] = *(short*)&b;
    }
    *(short8*)(xh + base + t * 16) = o0;
    *(short8*)(xh + base + t * 16 + 8) = o1;
}

// ---------------------------------------------------------------------------
// Kernel 3: out[m][o] = sum_k xh[m][k] * W4[o][k]  (bf16 in, fp32 out).
// K-loop/schedule UNCHANGED from measured 265 µs R7 state; epilogue now
// writes fp32 directly to the final output (fwht_out is folded into W4).
// ---------------------------------------------------------------------------
__global__ __launch_bounds__(512, 2) void gemm_bt(
    const __hip_bfloat16* __restrict__ xh,
    const __hip_bfloat16* __restrict__ wf,
    float* __restrict__ out)
{
    __shared__ __align__(16) __hip_bfloat16 sA[2][256 * 64];
    __shared__ __align__(16) __hip_bfloat16 sB[2][256 * 64];

    const int t = threadIdx.x;
    const int lane = t & 63;
    const int wv = t >> 6;
    const int wm = wv >> 2;
    const int wn = wv & 3;
    const long mBase = (long)blockIdx.y * 256;
    const long nBase = (long)blockIdx.x * 256;

    const int grow = t >> 3;
    const int gcol = ((t & 7) ^ (grow & 7)) * 8;
    const __hip_bfloat16* gA = xh + (mBase + grow) * 4096 + gcol;
    const __hip_bfloat16* gB = wf + (nBase + grow) * 4096 + gcol;
    const int lrow = wv * 8;

    const int fr = lane & 15;
    const int c2 = lane >> 4;
    const int slot0 = ((c2 ^ (fr & 7)) * 8);

    floatx4 acc[8][4] = {};
    short8 afr[4][2];
    short8 bfr[4][2];

    auto stage = [&](int buf, int isA, int halfRow, int kt) {
        const __hip_bfloat16* g =
            (isA ? gA : gB) + (long)halfRow * 4096 + (long)kt * 64;
        __hip_bfloat16* l =
            (isA ? &sA[buf][0] : &sB[buf][0]) + (halfRow + lrow) * 64;
        GLOAD_LDS16(g, l);
        GLOAD_LDS16(g + 64L * 4096, l + 64 * 64);
    };
    auto ldA = [&](int buf, int mhalf) {
        const __hip_bfloat16* base =
            &sA[buf][0] + (wm * 128 + mhalf * 64 + fr) * 64;
#pragma unroll
        for (int m = 0; m < 4; ++m) {
            afr[m][0] = *(const short8*)(base + m * 16 * 64 + slot0);
            afr[m][1] = *(const short8*)(base + m * 16 * 64 + (slot0 ^ 32));
        }
    };
    auto ldB2 = [&](int buf, int npair) {
        const __hip_bfloat16* base =
            &sB[buf][0] + (wn * 64 + npair * 32 + fr) * 64;
#pragma unroll
        for (int n = 0; n < 2; ++n) {
            bfr[npair * 2 + n][0] = *(const short8*)(base + n * 16 * 64 + slot0);
            bfr[npair * 2 + n][1] = *(const short8*)(base + n * 16 * 64 + (slot0 ^ 32));
        }
    };
    auto mma16 = [&](int mh, int np) {
#pragma unroll
        for (int m = 0; m < 4; ++m)
#pragma unroll
            for (int n = 0; n < 2; ++n)
#pragma unroll
                for (int kh = 0; kh < 2; ++kh)
                    acc[mh * 4 + m][np * 2 + n] =
                        __builtin_amdgcn_mfma_f32_16x16x32_bf16(
                            afr[m][kh], bfr[np * 2 + n][kh],
                            acc[mh * 4 + m][np * 2 + n], 0, 0, 0);
    };

    stage(0, 1, 0,   0);
    stage(0, 1, 128, 0);
    stage(0, 0, 0,   0);
    stage(0, 0, 128, 0);
    stage(1, 0, 0,   1);
    stage(1, 1, 0,   1);
    asm volatile("s_waitcnt vmcnt(4)" ::: "memory");
    BARRIER();

    for (int kt = 0; kt < 64; ++kt) {
        const int cur = kt & 1;

        ldA(cur, 0);
        ldB2(cur, 0);
        if (kt + 1 < 64) stage(cur ^ 1, 1, 128, kt + 1);
        __builtin_amdgcn_s_setprio(1);
        mma16(0, 0);
        __builtin_amdgcn_s_setprio(0);
        PHASE_END();

        ldB2(cur, 1);
        if (kt + 1 < 64) stage(cur ^ 1, 0, 128, kt + 1);
        __builtin_amdgcn_s_setprio(1);
        mma16(0, 1);
        __builtin_amdgcn_s_setprio(0);
        PHASE_END();

        ldA(cur, 1);
        if (kt + 2 < 64) stage(cur, 0, 0, kt + 2);
        __builtin_amdgcn_s_setprio(1);
        mma16(1, 0);
        __builtin_amdgcn_s_setprio(0);
        PHASE_END();

        if (kt + 2 < 64) stage(cur, 1, 0, kt + 2);
        __builtin_amdgcn_s_setprio(1);
        mma16(1, 1);
        __builtin_amdgcn_s_setprio(0);
        __builtin_amdgcn_sched_barrier(0);
        if (kt < 62) asm volatile("s_waitcnt vmcnt(4) lgkmcnt(0)" ::: "memory");
        else         asm volatile("s_waitcnt vmcnt(0) lgkmcnt(0)" ::: "memory");
        __builtin_amdgcn_s_barrier();
        __builtin_amdgcn_sched_barrier(0);
    }

    const int q4 = c2 * 4;
#pragma unroll
    for (int m = 0; m < 8; ++m)
#pragma unroll
        for (int n = 0; n < 4; ++n)
#pragma unroll
            for (int r = 0; r < 4; ++r) {
                const long row = mBase + wm * 128 + m * 16 + q4 + r;
                const long col = nBase + wn * 64 + n * 16 + fr;
                out[row * 4096 + col] = acc[m][n][r];
            }
}

// ---------------------------------------------------------------------------
extern "C" void kernel_launch(void* const* d_in, const int* in_sizes, int n_in,
                              void* d_out, int out_size, void* d_ws, size_t ws_size,
                              hipStream_t stream)
{
    const float* input  = (const float*)d_in[0];
    const int*   Qidxs  = (const int*)d_in[1];
    const float* D4_CB  = (const float*)d_in[2];
    const float* SU     = (const float*)d_in[3];
    const float* SV     = (const float*)d_in[4];
    const float* Wscale = (const float*)d_in[5];
    const float* A      = (const float*)d_in[6];
    const float* B      = (const float*)d_in[7];
    const float* sWH    = (const float*)d_in[8];
    float* out = (float*)d_out;

    char* ws = (char*)d_ws;
    __hip_bfloat16* w4   = (__hip_bfloat16*)ws;                               // 32 MiB
    __hip_bfloat16* xh   = (__hip_bfloat16*)(ws + (32L << 20));               // 64 MiB
    float*          wtmp = (float*)(ws + (32L << 20) + (64L << 20));          // 64 MiB

    decode_mfma<<<dim3(16, 16), 512, 0, stream>>>(Qidxs, D4_CB, Wscale, A, B, wtmp);
    wfwht_col_pass<<<dim3(256, 4), 256, 0, stream>>>(wtmp, wtmp, nullptr, nullptr, 0, 0);
    wfwht_col_pass<<<dim3(256, 4), 256, 0, stream>>>(wtmp, wtmp, nullptr, nullptr, 4, 0);
    wfwht_col_pass<<<dim3(256, 4), 256, 0, stream>>>(wtmp, nullptr, w4, SV, 8, 1);
    fwht_in_kernel<<<8192, 256, 0, stream>>>(input, SU, sWH, xh);
    gemm_bt<<<dim3(16, 32), 512, 0, stream>>>(xh, w4, out);
}

// Round 17
// 547.186 us; speedup vs baseline: 1.0814x; 1.0814x over previous
//
#include <hip/hip_runtime.h>
#include <hip/hip_bf16.h>
#include <stdint.h>

typedef __attribute__((ext_vector_type(8))) short short8;
typedef __attribute__((ext_vector_type(4))) float floatx4;

#define GLOAD_LDS16(gptr, lptr)                                                     \
  __builtin_amdgcn_global_load_lds(                                                 \
      (const __attribute__((address_space(1))) void*)(gptr),                        \
      (__attribute__((address_space(3))) void*)(lptr), 16, 0, 0)

#define FENCE() asm volatile("" ::: "memory")
#define BARRIER() do { FENCE(); __builtin_amdgcn_s_barrier(); FENCE(); } while (0)
#define PHASE_END() do { __builtin_amdgcn_sched_barrier(0);                        \
                         asm volatile("s_waitcnt lgkmcnt(0)" ::: "memory");        \
                         __builtin_amdgcn_s_barrier();                             \
                         __builtin_amdgcn_sched_barrier(0); } while (0)

__device__ inline void fwht16(float v[16]) {
#pragma unroll
    for (int s = 0; s < 4; ++s) {
        const int h = 1 << s;
#pragma unroll
        for (int k = 0; k < 16; k += 2 * h)
#pragma unroll
            for (int j = 0; j < h; ++j) {
                float a = v[k + j], b = v[k + j + h];
                v[k + j] = a + b;
                v[k + j + h] = a - b;
            }
    }
}

// ---------------------------------------------------------------------------
// Kernel 1: W_eff(bf16) = Wscale*CB[Qidxs] + (A@B) via bf16 MFMA.
// Reverted to the measured R11 state (552 µs pipeline).
// ---------------------------------------------------------------------------
__global__ __launch_bounds__(512) void decode_mfma(
    const int* __restrict__ Qidxs, const float* __restrict__ D4_CB,
    const float* __restrict__ Wscale_p, const float* __restrict__ A,
    const float* __restrict__ B, __hip_bfloat16* __restrict__ W_eff)
{
    __shared__ __align__(16) __hip_bfloat16 la[256 * 72];
    __shared__ __align__(16) __hip_bfloat16 lbt[256 * 72];
    __shared__ __align__(16) float CBs[1024];

    const int t = threadIdx.x;
    const int lane = t & 63;
    const int wv = t >> 6;
    const int wm = wv >> 2;           // 0..1  (o-half)
    const int wn = wv & 3;            // 0..3  (i-quarter)
    const long oBase = (long)blockIdx.y * 256;
    const long iBase = (long)blockIdx.x * 256;

#pragma unroll
    for (int u = 0; u < 8; ++u) {
        int el4 = u * 512 + t;          // float4 index, 4096 total
        int row = el4 >> 4;
        int r   = (el4 & 15) * 4;
        float4 v = *(const float4*)(A + (oBase + row) * 64 + r);
        __hip_bfloat16* d = &la[row * 72 + r];
        d[0] = __float2bfloat16(v.x); d[1] = __float2bfloat16(v.y);
        d[2] = __float2bfloat16(v.z); d[3] = __float2bfloat16(v.w);
    }
#pragma unroll
    for (int u = 0; u < 32; ++u) {
        int el = u * 512 + t;           // 0..16383
        int r = el >> 8;
        int j = el & 255;
        lbt[j * 72 + r] = __float2bfloat16(B[(long)r * 4096 + iBase + j]);
    }
    if (t < 256) ((float4*)CBs)[t] = ((const float4*)D4_CB)[t];
    __syncthreads();

    const float wscale = Wscale_p[0];
    const int fr = lane & 15;
    const int c2 = lane >> 4;
    floatx4 acc[8][4] = {};
    short8 af[4][2], bfx[4][2];

#pragma unroll
    for (int n = 0; n < 4; ++n)
#pragma unroll
        for (int kh = 0; kh < 2; ++kh)
            bfx[n][kh] = *(const short8*)&lbt[(wn * 64 + n * 16 + fr) * 72 + kh * 32 + c2 * 8];

#pragma unroll
    for (int mh = 0; mh < 2; ++mh) {
#pragma unroll
        for (int m = 0; m < 4; ++m)
#pragma unroll
            for (int kh = 0; kh < 2; ++kh)
                af[m][kh] = *(const short8*)&la[(wm * 128 + mh * 64 + m * 16 + fr) * 72 + kh * 32 + c2 * 8];
#pragma unroll
        for (int m = 0; m < 4; ++m)
#pragma unroll
            for (int n = 0; n < 4; ++n)
#pragma unroll
                for (int kh = 0; kh < 2; ++kh)
                    acc[mh * 4 + m][n] = __builtin_amdgcn_mfma_f32_16x16x32_bf16(
                        af[m][kh], bfx[n][kh], acc[mh * 4 + m][n], 0, 0, 0);
    }

    const int q4 = c2 * 4;
#pragma unroll
    for (int m = 0; m < 8; ++m)
#pragma unroll
        for (int n = 0; n < 4; ++n)
#pragma unroll
            for (int rr = 0; rr < 4; ++rr) {
                const long o = oBase + wm * 128 + m * 16 + q4 + rr;
                const long i = iBase + wn * 64 + n * 16 + fr;
                const int q = Qidxs[o * 1024 + (i >> 2)];
                const float w = wscale * CBs[q * 4 + (i & 3)] + acc[m][n][rr];
                W_eff[o * 4096 + i] = __float2bfloat16(w);
            }
}

// ---------------------------------------------------------------------------
// Kernel 2: per row: x*(SU/scaleWH) -> FWHT(4096) -> *1/64 -> bf16.
// R13: grid-stride over rows (2048 blocks x 4 rows, Guideline 11) with the
// per-thread scale vector (SU[e]*rcp(sWH[e]), e thread-fixed) hoisted out
// of the row loop. End-of-loop barrier protects LDS reuse across rows.
// ---------------------------------------------------------------------------
__global__ __launch_bounds__(256) void fwht_in_kernel(
    const float* __restrict__ x, const float* __restrict__ SU,
    const float* __restrict__ sWH, __hip_bfloat16* __restrict__ xh)
{
    __shared__ float row[4096 + 256];
    const int t = threadIdx.x;
    const int lo = t & 15, hi = t >> 4;

    float sc[16];
#pragma unroll
    for (int u = 0; u < 16; ++u) {
        int e = u * 256 + t;
        sc[u] = SU[e] * __builtin_amdgcn_rcpf(sWH[e]);
    }

    for (int rb = blockIdx.x; rb < 8192; rb += 2048) {
        const long base = (long)rb * 4096;
        float v[16];

#pragma unroll
        for (int u = 0; u < 16; ++u)
            v[u] = x[base + u * 256 + t] * sc[u];
        fwht16(v);
#pragma unroll
        for (int u = 0; u < 16; ++u) {
            int e = u * 256 + t;
            row[e + (e >> 4)] = v[u];
        }
        __syncthreads();

#pragma unroll
        for (int u = 0; u < 16; ++u) v[u] = row[hi * 272 + u * 17 + lo];
        fwht16(v);
#pragma unroll
        for (int u = 0; u < 16; ++u) row[hi * 272 + u * 17 + lo] = v[u];
        __syncthreads();

#pragma unroll
        for (int u = 0; u < 16; ++u) v[u] = row[t * 17 + u];
        fwht16(v);

        short8 o0, o1;
#pragma unroll
        for (int u = 0; u < 8; ++u) {
            __hip_bfloat16 b = __float2bfloat16(v[u] * 0.015625f);
            o0[u] = *(short*)&b;
        }
#pragma unroll
        for (int u = 0; u < 8; ++u) {
            __hip_bfloat16 b = __float2bfloat16(v[8 + u] * 0.015625f);
            o1[u] = *(short*)&b;
        }
        *(short8*)(xh + base + t * 16) = o0;
        *(short8*)(xh + base + t * 16 + 8) = o1;
        __syncthreads();   // all phase-C reads done before next row's writes
    }
}

// ---------------------------------------------------------------------------
// Kernel 3: z[m][n] = sum_k xh[m][k] * W_eff[n][k]   (bf16 in, bf16 out)
// 256x256 tile, BK=64, 512 thr. R7 single-trailing-barrier schedule —
// reverted to the measured 265 µs / 44.9% MfmaUtil R11 state (bf16 z out).
// ---------------------------------------------------------------------------
__global__ __launch_bounds__(512, 2) void gemm_bt(
    const __hip_bfloat16* __restrict__ xh,
    const __hip_bfloat16* __restrict__ wf,
    __hip_bfloat16* __restrict__ z)
{
    __shared__ __align__(16) __hip_bfloat16 sA[2][256 * 64];
    __shared__ __align__(16) __hip_bfloat16 sB[2][256 * 64];

    const int t = threadIdx.x;
    const int lane = t & 63;
    const int wv = t >> 6;
    const int wm = wv >> 2;
    const int wn = wv & 3;
    const long mBase = (long)blockIdx.y * 256;
    const long nBase = (long)blockIdx.x * 256;

    const int grow = t >> 3;
    const int gcol = ((t & 7) ^ (grow & 7)) * 8;
    const __hip_bfloat16* gA = xh + (mBase + grow) * 4096 + gcol;
    const __hip_bfloat16* gB = wf + (nBase + grow) * 4096 + gcol;
    const int lrow = wv * 8;

    const int fr = lane & 15;
    const int c2 = lane >> 4;
    const int slot0 = ((c2 ^ (fr & 7)) * 8);

    floatx4 acc[8][4] = {};
    short8 afr[4][2];
    short8 bfr[4][2];

    auto stage = [&](int buf, int isA, int halfRow, int kt) {
        const __hip_bfloat16* g =
            (isA ? gA : gB) + (long)halfRow * 4096 + (long)kt * 64;
        __hip_bfloat16* l =
            (isA ? &sA[buf][0] : &sB[buf][0]) + (halfRow + lrow) * 64;
        GLOAD_LDS16(g, l);
        GLOAD_LDS16(g + 64L * 4096, l + 64 * 64);
    };
    auto ldA = [&](int buf, int mhalf) {
        const __hip_bfloat16* base =
            &sA[buf][0] + (wm * 128 + mhalf * 64 + fr) * 64;
#pragma unroll
        for (int m = 0; m < 4; ++m) {
            afr[m][0] = *(const short8*)(base + m * 16 * 64 + slot0);
            afr[m][1] = *(const short8*)(base + m * 16 * 64 + (slot0 ^ 32));
        }
    };
    auto ldB2 = [&](int buf, int npair) {
        const __hip_bfloat16* base =
            &sB[buf][0] + (wn * 64 + npair * 32 + fr) * 64;
#pragma unroll
        for (int n = 0; n < 2; ++n) {
            bfr[npair * 2 + n][0] = *(const short8*)(base + n * 16 * 64 + slot0);
            bfr[npair * 2 + n][1] = *(const short8*)(base + n * 16 * 64 + (slot0 ^ 32));
        }
    };
    auto mma16 = [&](int mh, int np) {
#pragma unroll
        for (int m = 0; m < 4; ++m)
#pragma unroll
            for (int n = 0; n < 2; ++n)
#pragma unroll
                for (int kh = 0; kh < 2; ++kh)
                    acc[mh * 4 + m][np * 2 + n] =
                        __builtin_amdgcn_mfma_f32_16x16x32_bf16(
                            afr[m][kh], bfr[np * 2 + n][kh],
                            acc[mh * 4 + m][np * 2 + n], 0, 0, 0);
    };

    stage(0, 1, 0,   0);
    stage(0, 1, 128, 0);
    stage(0, 0, 0,   0);
    stage(0, 0, 128, 0);
    stage(1, 0, 0,   1);
    stage(1, 1, 0,   1);
    asm volatile("s_waitcnt vmcnt(4)" ::: "memory");
    BARRIER();

    for (int kt = 0; kt < 64; ++kt) {
        const int cur = kt & 1;

        ldA(cur, 0);
        ldB2(cur, 0);
        if (kt + 1 < 64) stage(cur ^ 1, 1, 128, kt + 1);
        __builtin_amdgcn_s_setprio(1);
        mma16(0, 0);
        __builtin_amdgcn_s_setprio(0);
        PHASE_END();

        ldB2(cur, 1);
        if (kt + 1 < 64) stage(cur ^ 1, 0, 128, kt + 1);
        __builtin_amdgcn_s_setprio(1);
        mma16(0, 1);
        __builtin_amdgcn_s_setprio(0);
        PHASE_END();

        ldA(cur, 1);
        if (kt + 2 < 64) stage(cur, 0, 0, kt + 2);
        __builtin_amdgcn_s_setprio(1);
        mma16(1, 0);
        __builtin_amdgcn_s_setprio(0);
        PHASE_END();

        if (kt + 2 < 64) stage(cur, 1, 0, kt + 2);
        __builtin_amdgcn_s_setprio(1);
        mma16(1, 1);
        __builtin_amdgcn_s_setprio(0);
        __builtin_amdgcn_sched_barrier(0);
        if (kt < 62) asm volatile("s_waitcnt vmcnt(4) lgkmcnt(0)" ::: "memory");
        else         asm volatile("s_waitcnt vmcnt(0) lgkmcnt(0)" ::: "memory");
        __builtin_amdgcn_s_barrier();
        __builtin_amdgcn_sched_barrier(0);
    }

    const int q4 = c2 * 4;
#pragma unroll
    for (int m = 0; m < 8; ++m)
#pragma unroll
        for (int n = 0; n < 4; ++n)
#pragma unroll
            for (int r = 0; r < 4; ++r) {
                const long row = mBase + wm * 128 + m * 16 + q4 + r;
                const long col = nBase + wn * 64 + n * 16 + fr;
                z[row * 4096 + col] = __float2bfloat16(acc[m][n][r]);
            }
}

// ---------------------------------------------------------------------------
// Kernel 4: per row: bf16 z -> FWHT(4096) -> *SV/64 -> fp32 out.
// R13: grid-stride (2048 blocks x 4 rows) + SV hoisted out of the row loop.
// ---------------------------------------------------------------------------
__global__ __launch_bounds__(256) void fwht_out_kernel(
    const __hip_bfloat16* __restrict__ z, const float* __restrict__ SV,
    float* __restrict__ out)
{
    __shared__ float row[4096 + 256];
    const int t = threadIdx.x;
    const int lo = t & 15, hi = t >> 4;

    float4 sv[4];
    {
        const float4* svv = (const float4*)(SV + t * 16);
#pragma unroll
        for (int c = 0; c < 4; ++c) {
            float4 s = svv[c];
            sv[c].x = s.x * 0.015625f; sv[c].y = s.y * 0.015625f;
            sv[c].z = s.z * 0.015625f; sv[c].w = s.w * 0.015625f;
        }
    }

    for (int rb = blockIdx.x; rb < 8192; rb += 2048) {
        const long base = (long)rb * 4096;
        float v[16];

#pragma unroll
        for (int u = 0; u < 16; ++u)
            v[u] = __bfloat162float(z[base + u * 256 + t]);
        fwht16(v);
#pragma unroll
        for (int u = 0; u < 16; ++u) {
            int e = u * 256 + t;
            row[e + (e >> 4)] = v[u];
        }
        __syncthreads();

#pragma unroll
        for (int u = 0; u < 16; ++u) v[u] = row[hi * 272 + u * 17 + lo];
        fwht16(v);
#pragma unroll
        for (int u = 0; u < 16; ++u) row[hi * 272 + u * 17 + lo] = v[u];
        __syncthreads();

#pragma unroll
        for (int u = 0; u < 16; ++u) v[u] = row[t * 17 + u];
        fwht16(v);

        float4* ov = (float4*)(out + base + t * 16);
#pragma unroll
        for (int c = 0; c < 4; ++c) {
            float4 f;
            f.x = v[4 * c + 0] * sv[c].x;
            f.y = v[4 * c + 1] * sv[c].y;
            f.z = v[4 * c + 2] * sv[c].z;
            f.w = v[4 * c + 3] * sv[c].w;
            ov[c] = f;
        }
        __syncthreads();   // all phase-C reads done before next row's writes
    }
}

// ---------------------------------------------------------------------------
extern "C" void kernel_launch(void* const* d_in, const int* in_sizes, int n_in,
                              void* d_out, int out_size, void* d_ws, size_t ws_size,
                              hipStream_t stream)
{
    const float* input  = (const float*)d_in[0];
    const int*   Qidxs  = (const int*)d_in[1];
    const float* D4_CB  = (const float*)d_in[2];
    const float* SU     = (const float*)d_in[3];
    const float* SV     = (const float*)d_in[4];
    const float* Wscale = (const float*)d_in[5];
    const float* A      = (const float*)d_in[6];
    const float* B      = (const float*)d_in[7];
    const float* sWH    = (const float*)d_in[8];
    float* out = (float*)d_out;

    char* ws = (char*)d_ws;
    __hip_bfloat16* weff = (__hip_bfloat16*)ws;                               // 32 MiB
    __hip_bfloat16* xh   = (__hip_bfloat16*)(ws + (32L << 20));               // 64 MiB
    __hip_bfloat16* zbuf = (__hip_bfloat16*)(ws + (32L << 20) + (64L << 20)); // 64 MiB

    decode_mfma<<<dim3(16, 16), 512, 0, stream>>>(Qidxs, D4_CB, Wscale, A, B, weff);
    fwht_in_kernel<<<2048, 256, 0, stream>>>(input, SU, sWH, xh);
    gemm_bt<<<dim3(16, 32), 512, 0, stream>>>(xh, weff, zbuf);
    fwht_out_kernel<<<2048, 256, 0, stream>>>(zbuf, SV, out);
}